// Round 12
// baseline (393.960 us; speedup 1.0000x reference)
//
#include <hip/hip_runtime.h>

#define T_DIM 8192
#define N_DIM 8
#define C_DIM 64
#define KB    2048
#define NT    (N_DIM * T_DIM)        // 65536 rows
#define TOTX  ((size_t)NT * C_DIM)   // 4194304 elements
#define ROWS_BLK 128
#define NBLK  (NT / ROWS_BLK)        // 512 blocks
#define LISTCAP 32768
#define TAU   0.25f

// Scratch inside out's x_d region (out + NT), overwritten LAST by xd_kernel.
// Offsets in FLOAT units from out+NT:
#define SCR_COUNT 0                   // int
#define SCR_LIST  16                  // int[32768]     -> ends 32784
#define SCR_PART  33024               // float[512][8]  -> ends 37120
#define SCR_KNS   40960               // float[2048]    -> ends 43008
#define SCR_KK    49152               // float[2048] np-exact ||k||^2 -> 51200
#define SCR_K     65536               // f16x8 khi[16][8][128] (256 KB) -> 131072

typedef _Float16 half_t;
typedef _Float16 f16x8 __attribute__((ext_vector_type(8)));
typedef float    f32x16 __attribute__((ext_vector_type(16)));

#define WAITL0() asm volatile("s_waitcnt lgkmcnt(0)" ::: "memory")
#define BAR()    __builtin_amdgcn_s_barrier()

// numpy pairwise sum (n=64) of squares (np-exact, for fixup path).
__device__ __forceinline__ float np_sumsq64(const float* __restrict__ a) {
    float r[8];
    #pragma unroll
    for (int j = 0; j < 8; ++j) r[j] = __fmul_rn(a[j], a[j]);
    #pragma unroll
    for (int i = 8; i < 64; i += 8)
        #pragma unroll
        for (int j = 0; j < 8; ++j)
            r[j] = __fadd_rn(r[j], __fmul_rn(a[i + j], a[i + j]));
    return __fadd_rn(__fadd_rn(__fadd_rn(r[0], r[1]), __fadd_rn(r[2], r[3])),
                     __fadd_rn(__fadd_rn(r[4], r[5]), __fadd_rn(r[6], r[7])));
}

// ------------------------------------------------------------------ k prep ----
// khi[bin>>7][slot][bin&127] = -2 * (f16)k  (hi part only; filter kernel).
// kns = sequential-fma ||k||^2 (filter offset); kk = np-exact ||k||^2 (fixup).
__global__ __launch_bounds__(256) void kprep_kernel(const float* __restrict__ k,
                                                    float* __restrict__ out) {
    float* base = out + NT;
    const int bin = blockIdx.x * 256 + threadIdx.x;   // grid 8 -> 2048
    if (bin == 0) ((int*)base)[SCR_COUNT] = 0;

    float kv[64];
    #pragma unroll
    for (int i = 0; i < 16; ++i)
        *(float4*)&kv[i * 4] = *(const float4*)(k + (size_t)bin * 64 + i * 4);

    float kn = 0.f;
    #pragma unroll
    for (int c = 0; c < 64; ++c) kn = fmaf(kv[c], kv[c], kn);
    base[SCR_KNS + bin] = kn;
    base[SCR_KK + bin]  = np_sumsq64(kv);

    f16x8* khi = (f16x8*)(base + SCR_K);
    const int ch = bin >> 7, b127 = bin & 127;
    #pragma unroll
    for (int slot = 0; slot < 8; ++slot) {
        f16x8 h8;
        #pragma unroll
        for (int e = 0; e < 8; ++e)
            h8[e] = (half_t)(-2.f * (float)((half_t)kv[slot * 8 + e]));
        khi[(size_t)ch * 1024 + slot * 128 + b127] = h8;
    }
}

// ------------------------------------------------------------------ argmin ----
// 256 threads (4 waves), 128 rows/block, hi-only filter. B-frags reg-loaded
// from L2 (distance-2 prefetch, 4 rotating buffers). Packed (value|bin) keys.
__global__ __launch_bounds__(256, 2) void argmin_kernel(const float* __restrict__ x,
                                                        const float* __restrict__ mask,
                                                        float* __restrict__ out) {
    __shared__ __align__(16) f16x8 xhi_s[1024];       // [8 slots][128 rows]
    __shared__ float kns_s[2048];
    __shared__ float sxh[256], sxxh[256];
    __shared__ float wacc[32];

    float* base = out + NT;
    const int tid = threadIdx.x;
    const int l   = tid & 63, w = tid >> 6;
    const int col = l & 31, kg = l >> 5;
    const int r0  = blockIdx.x * ROWS_BLK;
    const int n   = r0 >> 13;
    const int t0  = r0 & (T_DIM - 1);

    #pragma unroll
    for (int i = 0; i < 8; ++i)
        kns_s[i * 256 + tid] = base[SCR_KNS + i * 256 + tid];

    // x prologue: load + f16-hi split + row stats
    {
        const int row = tid & 127, chalf = tid >> 7;
        float xv[32];
        #pragma unroll
        for (int j = 0; j < 32; ++j)
            xv[j] = x[((size_t)n * C_DIM + chalf * 32 + j) * T_DIM + t0 + row];
        float sx = 0.f, sxx = 0.f;
        #pragma unroll
        for (int j = 0; j < 32; ++j) { sx += xv[j]; sxx = fmaf(xv[j], xv[j], sxx); }
        sxh[chalf * 128 + row]  = sx;
        sxxh[chalf * 128 + row] = sxx;
        #pragma unroll
        for (int j4 = 0; j4 < 4; ++j4) {
            f16x8 h8;
            #pragma unroll
            for (int e = 0; e < 8; ++e) h8[e] = (half_t)xv[j4 * 8 + e];
            xhi_s[(chalf * 4 + j4) * 128 + row] = h8;
        }
    }
    WAITL0(); BAR();

    const int arow = w * 32 + col;
    f16x8 a0 = xhi_s[(0 + kg) * 128 + arow];
    f16x8 a1 = xhi_s[(2 + kg) * 128 + arow];
    f16x8 a2 = xhi_s[(4 + kg) * 128 + arow];
    f16x8 a3 = xhi_s[(6 + kg) * 128 + arow];

    const f16x8* kf = (const f16x8*)(base + SCR_K) + kg * 128 + col;

    f32x16 zacc;
    #pragma unroll
    for (int r = 0; r < 16; ++r) zacc[r] = 0.f;

    float bestf[16], best2f[16];
    #pragma unroll
    for (int r = 0; r < 16; ++r) { bestf[r] = __builtin_inff(); best2f[r] = __builtin_inff(); }

    f16x8 bA0, bA1, bA2, bA3, bB0, bB1, bB2, bB3;
    f16x8 bC0, bC1, bC2, bC3, bD0, bD1, bD2, bD3;
    float knA, knB, knC, knD;

#define LOAD(t, B0, B1, B2, B3, KN)                                  \
    {                                                                \
        const f16x8* p = kf + (((t) >> 2) * 1024 + ((t) & 3) * 32);  \
        B0 = p[0]; B1 = p[256]; B2 = p[512]; B3 = p[768];            \
        KN = kns_s[(t) * 32 + col];                                  \
    }

#define COMP(t, B0, B1, B2, B3, KN)                                          \
    {                                                                        \
        f32x16 acc = __builtin_amdgcn_mfma_f32_32x32x16_f16(a0, B0, zacc, 0, 0, 0); \
        acc = __builtin_amdgcn_mfma_f32_32x32x16_f16(a1, B1, acc, 0, 0, 0);  \
        acc = __builtin_amdgcn_mfma_f32_32x32x16_f16(a2, B2, acc, 0, 0, 0);  \
        acc = __builtin_amdgcn_mfma_f32_32x32x16_f16(a3, B3, acc, 0, 0, 0);  \
        const unsigned binf = (t) * 32 + col;                                \
        _Pragma("unroll")                                                    \
        for (int r = 0; r < 16; ++r) {                                       \
            float sv = acc[r] + KN;                                          \
            float spf = __uint_as_float((__float_as_uint(sv) & ~2047u) | binf); \
            best2f[r] = fminf(best2f[r], fmaxf(spf, bestf[r]));              \
            bestf[r]  = fminf(bestf[r], spf);                                \
        }                                                                    \
    }

    LOAD(0, bA0, bA1, bA2, bA3, knA);
    LOAD(1, bB0, bB1, bB2, bB3, knB);
    #pragma unroll 1
    for (int t = 0; t < 56; t += 4) {
        LOAD(t + 2, bC0, bC1, bC2, bC3, knC); COMP(t,     bA0, bA1, bA2, bA3, knA);
        LOAD(t + 3, bD0, bD1, bD2, bD3, knD); COMP(t + 1, bB0, bB1, bB2, bB3, knB);
        LOAD(t + 4, bA0, bA1, bA2, bA3, knA); COMP(t + 2, bC0, bC1, bC2, bC3, knC);
        LOAD(t + 5, bB0, bB1, bB2, bB3, knB); COMP(t + 3, bD0, bD1, bD2, bD3, knD);
    }
    LOAD(58, bC0, bC1, bC2, bC3, knC); COMP(56, bA0, bA1, bA2, bA3, knA);
    LOAD(59, bD0, bD1, bD2, bD3, knD); COMP(57, bB0, bB1, bB2, bB3, knB);
    LOAD(60, bA0, bA1, bA2, bA3, knA); COMP(58, bC0, bC1, bC2, bC3, knC);
    LOAD(61, bB0, bB1, bB2, bB3, knB); COMP(59, bD0, bD1, bD2, bD3, knD);
    LOAD(62, bC0, bC1, bC2, bC3, knC); COMP(60, bA0, bA1, bA2, bA3, knA);
    LOAD(63, bD0, bD1, bD2, bD3, knD); COMP(61, bB0, bB1, bB2, bB3, knB);
    COMP(62, bC0, bC1, bC2, bC3, knC);
    COMP(63, bD0, bD1, bD2, bD3, knD);
#undef LOAD
#undef COMP

    // merge across the 32 column-lanes (packed keys: value+index together)
    #pragma unroll
    for (int off = 1; off <= 16; off <<= 1) {
        #pragma unroll
        for (int r = 0; r < 16; ++r) {
            float ov = __shfl_xor(bestf[r], off, 64);
            float o2 = __shfl_xor(best2f[r], off, 64);
            float mx = fmaxf(bestf[r], ov);
            best2f[r] = fminf(fminf(best2f[r], o2), mx);
            bestf[r]  = fminf(bestf[r], ov);
        }
    }

    // write-out (lanes col==0 of each half own 16 rows each)
    float s0 = 0.f, s1 = 0.f, s2 = 0.f, s3 = 0.f, s4 = 0.f;
    if (col == 0) {
        int* countp = (int*)base + SCR_COUNT;
        int* listp  = (int*)base + SCR_LIST;
        #pragma unroll
        for (int r = 0; r < 16; ++r) {
            const int row_loc = w * 32 + 4 * kg + (r & 3) + 8 * (r >> 2);
            const int grow = r0 + row_loc;
            const unsigned bbits = __float_as_uint(bestf[r]);
            const float bval  = __uint_as_float(bbits & ~2047u);
            const float b2val = __uint_as_float(__float_as_uint(best2f[r]) & ~2047u);
            out[grow] = (float)(bbits & 2047u);
            if (b2val - bval < TAU) {
                int idx = atomicAdd(countp, 1);
                if (idx < LISTCAP) listp[idx] = grow;
            }
            const float m   = mask[grow];
            const float sxx = sxxh[row_loc] + sxxh[128 + row_loc];
            const float d2  = sxx + bval;
            s0 = fmaf(m, d2, s0); s1 += d2; s2 += m;
            s3 += sxh[row_loc] + sxh[128 + row_loc];
            s4 += sxx;
        }
    }
    s0 += __shfl_xor(s0, 32, 64);
    s1 += __shfl_xor(s1, 32, 64);
    s2 += __shfl_xor(s2, 32, 64);
    s3 += __shfl_xor(s3, 32, 64);
    s4 += __shfl_xor(s4, 32, 64);
    if (l == 0) {
        wacc[w * 8 + 0] = s0; wacc[w * 8 + 1] = s1; wacc[w * 8 + 2] = s2;
        wacc[w * 8 + 3] = s3; wacc[w * 8 + 4] = s4;
    }
    WAITL0(); BAR();
    if (tid == 0) {
        float* partials = base + SCR_PART;
        #pragma unroll
        for (int q = 0; q < 5; ++q)
            partials[(size_t)blockIdx.x * 8 + q] =
                wacc[0 * 8 + q] + wacc[1 * 8 + q] + wacc[2 * 8 + q] + wacc[3 * 8 + q];
    }
}

// ------------------------------------------------------------------ fixup ----
// np-f32-exact recompute of flagged rows (precomputed np-exact kk).
__global__ __launch_bounds__(256) void fixup_kernel(const float* __restrict__ x,
                                                    const float* __restrict__ k,
                                                    float* __restrict__ out) {
    __shared__ float xv[C_DIM];
    __shared__ float sxxs;
    __shared__ float redv[4];
    __shared__ int   redb[4];
    const int tid = threadIdx.x;
    const float* base = out + NT;
    const int* count    = (const int*)base + SCR_COUNT;
    const int* flaglist = (const int*)base + SCR_LIST;
    int cnt = *count;
    if (cnt > LISTCAP) cnt = LISTCAP;

    for (int it = blockIdx.x; it < cnt; it += gridDim.x) {
        const int row = flaglist[it];
        const int n = row >> 13, t = row & (T_DIM - 1);
        if (tid < C_DIM)
            xv[tid] = x[((size_t)n * C_DIM + tid) * T_DIM + t];
        __syncthreads();
        if (tid == 0) sxxs = np_sumsq64(xv);
        __syncthreads();
        const float xx = sxxs;

        float bv = __builtin_inff();
        int   bb = 0x7fffffff;
        for (int b = tid; b < KB; b += 256) {
            const float* kr = k + (size_t)b * C_DIM;
            float dot = 0.f;
            #pragma unroll
            for (int c = 0; c < C_DIM; ++c)
                dot = fmaf(xv[c], kr[c], dot);
            float kk = base[SCR_KK + b];
            float d  = __fadd_rn(__fsub_rn(xx, __fadd_rn(dot, dot)), kk);
            if (d < bv) { bv = d; bb = b; }
        }
        #pragma unroll
        for (int off = 1; off <= 32; off <<= 1) {
            float ov = __shfl_xor(bv, off, 64);
            int   ob = __shfl_xor(bb, off, 64);
            if (ov < bv || (ov == bv && ob < bb)) { bv = ov; bb = ob; }
        }
        const int wid = tid >> 6, lane = tid & 63;
        if (lane == 0) { redv[wid] = bv; redb[wid] = bb; }
        __syncthreads();
        if (tid == 0) {
            float fv = redv[0]; int fb = redb[0];
            #pragma unroll
            for (int wq = 1; wq < 4; ++wq) {
                if (redv[wq] < fv || (redv[wq] == fv && redb[wq] < fb)) {
                    fv = redv[wq]; fb = redb[wq];
                }
            }
            out[row] = (float)fb;
        }
        __syncthreads();
    }
}

// ------------------------------------------------------------- finalize ----
__global__ __launch_bounds__(256) void finalize_kernel(float* __restrict__ out) {
    const float* partials = (out + NT) + SCR_PART;
    const int tid = threadIdx.x;
    double vals[5] = {0, 0, 0, 0, 0};
    for (int i = tid; i < NBLK; i += 256)
        #pragma unroll
        for (int q = 0; q < 5; ++q) vals[q] += (double)partials[(size_t)i * 8 + q];
    #pragma unroll
    for (int off = 1; off <= 32; off <<= 1)
        #pragma unroll
        for (int q = 0; q < 5; ++q) vals[q] += __shfl_xor(vals[q], off, 64);
    __shared__ double sred[4][5];
    const int wid = tid >> 6, lane = tid & 63;
    if (lane == 0)
        for (int q = 0; q < 5; ++q) sred[wid][q] = vals[q];
    __syncthreads();
    if (tid == 0) {
        double cm  = sred[0][0] + sred[1][0] + sred[2][0] + sred[3][0];
        double fs  = sred[0][1] + sred[1][1] + sred[2][1] + sred[3][1];
        double ms  = sred[0][2] + sred[1][2] + sred[2][2] + sred[3][2];
        double sx  = sred[0][3] + sred[1][3] + sred[2][3] + sred[3][3];
        double sxx = sred[0][4] + sred[1][4] + sred[2][4] + sred[3][4];
        double sz  = (double)TOTX;
        out[NT + TOTX + 0] = (float)(cm / (ms * (double)C_DIM));
        out[NT + TOTX + 1] = (float)(fs / (double)NT);
        out[NT + TOTX + 2] = (float)sqrt(fmax(0.0, (sxx - sx * sx / sz) / sz));
    }
}

// --------------------------------------------------------------------- x_d ----
// Runs LAST: overwrites the scratch region with real x_d values.
__global__ __launch_bounds__(256) void xd_kernel(const float* __restrict__ mask,
                                                 const float* __restrict__ k,
                                                 float* __restrict__ out) {
    const int row = blockIdx.x * 256 + threadIdx.x;
    const int n = row >> 13, t = row & (T_DIM - 1);
    const int b = (int)out[row];
    const float m = mask[row];
    const float* kr = k + (size_t)b * C_DIM;
    float* xd = out + NT;
    #pragma unroll
    for (int c = 0; c < C_DIM; ++c)
        xd[((size_t)n * C_DIM + c) * T_DIM + t] = kr[c] * m;
}

// ----------------------------------------------------------------- launch ----
extern "C" void kernel_launch(void* const* d_in, const int* in_sizes, int n_in,
                              void* d_out, int out_size, void* d_ws, size_t ws_size,
                              hipStream_t stream) {
    (void)in_sizes; (void)n_in; (void)out_size; (void)d_ws; (void)ws_size;
    const float* x    = (const float*)d_in[0];
    const float* mask = (const float*)d_in[1];
    const float* k    = (const float*)d_in[2];
    float* out = (float*)d_out;

    kprep_kernel<<<KB / 256, 256, 0, stream>>>(k, out);
    argmin_kernel<<<NBLK, 256, 0, stream>>>(x, mask, out);
    fixup_kernel<<<1024, 256, 0, stream>>>(x, k, out);
    finalize_kernel<<<1, 256, 0, stream>>>(out);
    xd_kernel<<<NT / 256, 256, 0, stream>>>(mask, k, out);
}